// Round 6
// baseline (479.865 us; speedup 1.0000x reference)
//
#include <hip/hip_runtime.h>

#define HID 512
#define OUTD 7
#define EPSV 1e-5f

typedef __attribute__((ext_vector_type(8))) short bf16x8;
typedef __attribute__((ext_vector_type(4))) float f32x4;
typedef unsigned short ushort_t;
typedef unsigned int uint_t;

// ---------------- bf16 helpers ----------------
__device__ __forceinline__ ushort_t f2bf(float f) {
    uint_t u = __float_as_uint(f);
    u = (u + 0x7fffu + ((u >> 16) & 1u)) >> 16;    // RNE
    return (ushort_t)u;
}
__device__ __forceinline__ float bflo(uint_t u) { return __uint_as_float(u << 16); }
__device__ __forceinline__ float bfhi(uint_t u) { return __uint_as_float(u & 0xffff0000u); }

// async global->LDS, 16B per lane; LDS dest is wave-uniform base + lane*16
__device__ __forceinline__ void gload_lds16(const ushort_t* g, ushort_t* l) {
    __builtin_amdgcn_global_load_lds(
        (const __attribute__((address_space(1))) uint_t*)g,
        (__attribute__((address_space(3))) uint_t*)l, 16, 0, 0);
}

// ---------------- setup ----------------

__global__ void zero_deg(int* __restrict__ deg, int N) {
    int i = blockIdx.x * blockDim.x + threadIdx.x;
    if (i < N) deg[i] = 0;
}

// degree count + all weight transposes (independent work, grid-partitioned)
__global__ void setup2(const int* __restrict__ dst, int* __restrict__ deg, int E,
                       const float* __restrict__ W0, const float* __restrict__ W1,
                       const float* __restrict__ W2, const float* __restrict__ W3,
                       ushort_t* __restrict__ T0, ushort_t* __restrict__ T1,
                       ushort_t* __restrict__ T2, ushort_t* __restrict__ T3) {
    int i = blockIdx.x * blockDim.x + threadIdx.x;
    if (i < E) { atomicAdd(&deg[dst[i]], 1); return; }
    i -= E;
    const int S0 = 128 * HID, S1 = HID * HID;
    if (i < S0) { int k = i / HID, n = i % HID; T0[(size_t)n * 128 + k] = f2bf(W0[i]); return; }
    i -= S0;
    if (i < S1) { int k = i / HID, n = i % HID; T1[(size_t)n * HID + k] = f2bf(W1[i]); return; }
    i -= S1;
    if (i < S1) { int k = i / HID, n = i % HID; T2[(size_t)n * HID + k] = f2bf(W2[i]); return; }
    i -= S1;
    if (i < S1) { int k = i / HID, n = i % HID; T3[(size_t)n * HID + k] = f2bf(W3[i]); }
}

// ---------------- hierarchical scan (3 phases) ----------------

__global__ void scan1(const int* __restrict__ deg, int* __restrict__ off,
                      int* __restrict__ partial, float* __restrict__ dinv, int N) {
    __shared__ int s[256];
    const int t = threadIdx.x;
    const int i = blockIdx.x * 256 + t;
    int d = (i < N) ? deg[i] : 0;
    if (i < N) dinv[i] = rsqrtf((float)(d + 1));   // +1 self loop
    s[t] = d;
    __syncthreads();
#pragma unroll
    for (int ofs = 1; ofs < 256; ofs <<= 1) {
        int v = (t >= ofs) ? s[t - ofs] : 0;
        __syncthreads();
        s[t] += v;
        __syncthreads();
    }
    if (i < N) off[i] = s[t] - d;
    if (t == 255) partial[blockIdx.x] = s[255];
}

__global__ void scan2(int* __restrict__ partial, int nb) {
    __shared__ int s[256];
    const int t = threadIdx.x;
    int d = (t < nb) ? partial[t] : 0;
    s[t] = d;
    __syncthreads();
#pragma unroll
    for (int ofs = 1; ofs < 256; ofs <<= 1) {
        int v = (t >= ofs) ? s[t - ofs] : 0;
        __syncthreads();
        s[t] += v;
        __syncthreads();
    }
    if (t < nb) partial[t] = s[t] - d;
}

__global__ void scan3(int* __restrict__ off, const int* __restrict__ partial,
                      int* __restrict__ cursor, int N, int E) {
    int i = blockIdx.x * blockDim.x + threadIdx.x;
    if (i < N) {
        int v = off[i] + partial[i >> 8];
        off[i] = v;
        cursor[i] = v;
    } else if (i == N) {
        off[N] = E;
    }
}

// ---------------- fused: CSR fill + x -> bf16*dinv + gsum zero ----------------

__global__ void fill_cvt(const int* __restrict__ src, const int* __restrict__ dst,
                         int* __restrict__ cursor, int* __restrict__ srcs, int E,
                         const float* __restrict__ x, const float* __restrict__ dinv,
                         ushort_t* __restrict__ xb, int totalx, float* __restrict__ gsum) {
    int i = blockIdx.x * blockDim.x + threadIdx.x;
    if (i < E) { int p = atomicAdd(&cursor[dst[i]], 1); srcs[p] = src[i]; return; }
    i -= E;
    if (i < totalx) { xb[i] = f2bf(x[i] * dinv[i >> 7]); return; }
    i -= totalx;
    if (i < HID) gsum[i] = 0.0f;
}

// ---------------- aggregation: column-tiled CSR gather (no per-edge weights) ----------------
// Input xs is PRE-SCALED by dinv (xs[r] = h[r]*dinv[r] in bf16).
// ax[r] = dinv[r] * (xs[r] + sum_{s in N(r)} xs[s]).
// ROWU = uints per row (64 for K=128, 256 for K=512). blockIdx.y = column tile
// (64 uints = 128 cols): per-tile source region ~5.1 MB ~ per-XCD L2, and tiles
// dispatch in y-major order => all resident waves gather from one tile at a time.
template<int ROWU>
__global__ __launch_bounds__(256) void csr_agg(
        const uint_t* __restrict__ xs, const int* __restrict__ off,
        const int* __restrict__ srcs, const float* __restrict__ dinv,
        uint_t* __restrict__ ax, int N) {
    int gtid = blockIdx.x * 256 + threadIdx.x;
    int r = gtid >> 6, lane = gtid & 63;
    if (r >= N) return;
    const int cofs = blockIdx.y * 64 + lane;
    const uint_t* xc = xs + cofs;
    uint_t v = xc[(size_t)r * ROWU];
    float a0 = bflo(v), a1 = bfhi(v);
    int e = off[r];
    const int e1 = off[r + 1];
    for (; e + 8 <= e1; e += 8) {
        int si[8]; uint_t vi[8];
#pragma unroll
        for (int j = 0; j < 8; j++) si[j] = srcs[e + j];
#pragma unroll
        for (int j = 0; j < 8; j++) vi[j] = xc[(size_t)si[j] * ROWU];
#pragma unroll
        for (int j = 0; j < 8; j++) { a0 += bflo(vi[j]); a1 += bfhi(vi[j]); }
    }
    for (; e + 2 <= e1; e += 2) {
        int s0 = srcs[e], s1 = srcs[e + 1];
        uint_t v0 = xc[(size_t)s0 * ROWU];
        uint_t v1 = xc[(size_t)s1 * ROWU];
        a0 += bflo(v0) + bflo(v1);
        a1 += bfhi(v0) + bfhi(v1);
    }
    if (e < e1) {
        uint_t vv = xc[(size_t)srcs[e] * ROWU];
        a0 += bflo(vv); a1 += bfhi(vv);
    }
    float dr = dinv[r];
    ax[(size_t)r * ROWU + cofs] = (uint_t)f2bf(a0 * dr) | ((uint_t)f2bf(a1 * dr) << 16);
}

// ---------------- MFMA GEMM: C[M x 512] = A[M x K](bf16) @ Wt[512 x K]^T + bias, bf16 out ----
// 128x128 tile, BK=32, 4 waves (64x64 each, 4x4 frags of 16x16x32).
// LDS chunk-major [chunk 0..3][row 0..127][8 bf16] — global_load_lds-compatible,
// conflict-free ds_read_b128 (lane stride 16B).

__global__ __launch_bounds__(256) void gemm_mfma(
        const ushort_t* __restrict__ A, const ushort_t* __restrict__ Wt,
        const float* __restrict__ bias, ushort_t* __restrict__ C, int M, int K) {
    __shared__ __align__(16) ushort_t As[4 * 128 * 8];   // 8 KB
    __shared__ __align__(16) ushort_t Bs[4 * 128 * 8];   // 8 KB
    const int t = threadIdx.x;
    const int wave = t >> 6, lane = t & 63;
    const int m0 = blockIdx.y * 128, n0 = blockIdx.x * 128;
    const int wm = (wave & 1) * 64, wn = (wave >> 1) * 64;
    const int quad = lane >> 4, l16 = lane & 15;

    f32x4 acc[4][4];
#pragma unroll
    for (int i = 0; i < 4; i++)
#pragma unroll
        for (int j = 0; j < 4; j++) acc[i][j] = (f32x4){0.f, 0.f, 0.f, 0.f};

    for (int k0 = 0; k0 < K; k0 += 32) {
        const int c = wave;   // wave stages its own k-chunk
#pragma unroll
        for (int h = 0; h < 2; h++) {
            int gm = m0 + 64 * h + lane;
            if (gm >= M) gm = M - 1;
            gload_lds16(A + (size_t)gm * K + k0 + c * 8, &As[(c * 128 + 64 * h) * 8]);
            gload_lds16(Wt + (size_t)(n0 + 64 * h + lane) * K + k0 + c * 8,
                        &Bs[(c * 128 + 64 * h) * 8]);
        }
        __syncthreads();
        bf16x8 af[4], bfr[4];
#pragma unroll
        for (int i = 0; i < 4; i++) {
            af[i]  = *(const bf16x8*)&As[(quad * 128 + wm + i * 16 + l16) * 8];
            bfr[i] = *(const bf16x8*)&Bs[(quad * 128 + wn + i * 16 + l16) * 8];
        }
#pragma unroll
        for (int i = 0; i < 4; i++)
#pragma unroll
            for (int jn = 0; jn < 4; jn++)
                acc[i][jn] = __builtin_amdgcn_mfma_f32_16x16x32_bf16(
                                 af[i], bfr[jn], acc[i][jn], 0, 0, 0);
        __syncthreads();
    }
    // epilogue: + bias, pack bf16. D: col = lane&15, row = quad*4 + reg
#pragma unroll
    for (int i = 0; i < 4; i++) {
#pragma unroll
        for (int jn = 0; jn < 4; jn++) {
            int gn = n0 + wn + jn * 16 + l16;
            float bv = bias[gn];
#pragma unroll
            for (int rg = 0; rg < 4; rg++) {
                int gm = m0 + wm + i * 16 + quad * 4 + rg;
                if (gm < M) C[(size_t)gm * HID + gn] = f2bf(acc[i][jn][rg] + bv);
            }
        }
    }
}

// ---------------- LayerNorm + ReLU (+ optional dinv pre-scale for next agg) ----------------

template<bool SCALE>
__global__ void ln_relu_bf16(const ushort_t* __restrict__ h, const float* __restrict__ gamma,
                             const float* __restrict__ beta, const float* __restrict__ dinv,
                             ushort_t* __restrict__ o, int N) {
    int gtid = blockIdx.x * blockDim.x + threadIdx.x;
    int r = gtid >> 6, lane = gtid & 63;
    if (r >= N) return;
    uint4 v = ((const uint4*)(h + (size_t)r * HID))[lane];
    float f[8] = {bflo(v.x), bfhi(v.x), bflo(v.y), bfhi(v.y),
                  bflo(v.z), bfhi(v.z), bflo(v.w), bfhi(v.w)};
    float s = 0.f, q = 0.f;
#pragma unroll
    for (int j = 0; j < 8; j++) { s += f[j]; q += f[j] * f[j]; }
#pragma unroll
    for (int ofs = 32; ofs > 0; ofs >>= 1) {
        s += __shfl_xor(s, ofs);
        q += __shfl_xor(q, ofs);
    }
    float mu  = s * (1.0f / HID);
    float var = q * (1.0f / HID) - mu * mu;
    float rs  = rsqrtf(var + EPSV);
    float dr  = SCALE ? dinv[r] : 1.0f;
    const float4* gp = (const float4*)gamma;
    const float4* bp = (const float4*)beta;
    float4 g0 = gp[2 * lane], g1 = gp[2 * lane + 1];
    float4 b0 = bp[2 * lane], b1 = bp[2 * lane + 1];
    float gg[8] = {g0.x, g0.y, g0.z, g0.w, g1.x, g1.y, g1.z, g1.w};
    float bb[8] = {b0.x, b0.y, b0.z, b0.w, b1.x, b1.y, b1.z, b1.w};
    uint_t pk[4];
#pragma unroll
    for (int j = 0; j < 4; j++) {
        float r0 = fmaxf((f[2*j]   - mu) * rs * gg[2*j]   + bb[2*j],   0.f) * dr;
        float r1 = fmaxf((f[2*j+1] - mu) * rs * gg[2*j+1] + bb[2*j+1], 0.f) * dr;
        pk[j] = (uint_t)f2bf(r0) | ((uint_t)f2bf(r1) << 16);
    }
    uint4 ov; ov.x = pk[0]; ov.y = pk[1]; ov.z = pk[2]; ov.w = pk[3];
    ((uint4*)(o + (size_t)r * HID))[lane] = ov;
}

// ---------------- mean pool + output head ----------------

__global__ void colsum(const ushort_t* __restrict__ h, float* __restrict__ gsum, int N) {
    int t = threadIdx.x;   // 256 -> 2 cols each
    float a0 = 0.f, a1 = 0.f;
    for (int r = blockIdx.x; r < N; r += gridDim.x) {
        uint_t u = ((const uint_t*)(h + (size_t)r * HID))[t];
        a0 += bflo(u);
        a1 += bfhi(u);
    }
    atomicAdd(&gsum[2 * t], a0);
    atomicAdd(&gsum[2 * t + 1], a1);
}

__global__ void out_kernel(const float* __restrict__ gsum, const float* __restrict__ Wout,
                           const float* __restrict__ bout, float* __restrict__ out, int N) {
    __shared__ float red[256];
    int t = threadIdx.x;
    float g0 = gsum[2 * t], g1 = gsum[2 * t + 1];
    float invn = 1.0f / (float)N;
    for (int o = 0; o < OUTD; o++) {
        float p = g0 * Wout[(2 * t) * OUTD + o] + g1 * Wout[(2 * t + 1) * OUTD + o];
        red[t] = p;
        __syncthreads();
        for (int sft = 128; sft > 0; sft >>= 1) {
            if (t < sft) red[t] += red[t + sft];
            __syncthreads();
        }
        if (t == 0) out[o] = red[0] * invn + bout[o];
        __syncthreads();
    }
}

// ---------------- launch ----------------

extern "C" void kernel_launch(void* const* d_in, const int* in_sizes, int n_in,
                              void* d_out, int out_size, void* d_ws, size_t ws_size,
                              hipStream_t stream) {
    const float* x  = (const float*)d_in[0];
    const int*   ei = (const int*)d_in[1];
    const int N = in_sizes[0] / 128;
    const int E = in_sizes[1] / 2;
    const int* src = ei;
    const int* dst = ei + E;
    const float* Ws[4] = {(const float*)d_in[2], (const float*)d_in[4],
                          (const float*)d_in[6], (const float*)d_in[8]};
    const float* bs[4] = {(const float*)d_in[3], (const float*)d_in[5],
                          (const float*)d_in[7], (const float*)d_in[9]};
    const float* gamma = (const float*)d_in[10];
    const float* beta  = (const float*)d_in[11];
    const float* Wout  = (const float*)d_in[12];
    const float* bout  = (const float*)d_in[13];
    float* out = (float*)d_out;

    // workspace layout (16B-aligned chunks first)
    char* p = (char*)d_ws;
    ushort_t* axb = (ushort_t*)p;  p += sizeof(ushort_t) * (size_t)N * HID;   // agg out / gemm A
    ushort_t* hb  = (ushort_t*)p;  p += sizeof(ushort_t) * (size_t)N * HID;   // gemm out (pre-LN)
    ushort_t* ho  = (ushort_t*)p;  p += sizeof(ushort_t) * (size_t)N * HID;   // LN out (layer input)
    ushort_t* xb  = ho;            // alias: x-bf16 (N*128, pre-scaled) until ln(l0) overwrites
    ushort_t* Wt[4];
    Wt[0] = (ushort_t*)p;          p += sizeof(ushort_t) * 128 * HID;
    Wt[1] = (ushort_t*)p;          p += sizeof(ushort_t) * HID * HID;
    Wt[2] = (ushort_t*)p;          p += sizeof(ushort_t) * HID * HID;
    Wt[3] = (ushort_t*)p;          p += sizeof(ushort_t) * HID * HID;
    float* dinv = (float*)p;       p += sizeof(float) * N;
    float* gsum = (float*)p;       p += sizeof(float) * HID;
    int* deg    = (int*)p;         p += sizeof(int) * N;
    int* off    = (int*)p;         p += sizeof(int) * (N + 4);
    int* cursor = (int*)p;         p += sizeof(int) * N;
    int* partial= (int*)p;         p += sizeof(int) * 256;
    int* srcs   = (int*)p;         // E ints

    const int nb = (N + 255) / 256;

    // ---- setup: CSR build + conversions (once) ----
    zero_deg<<<(N + 255) / 256, 256, 0, stream>>>(deg, N);
    {
        int tot = E + 128 * HID + 3 * HID * HID;
        setup2<<<(tot + 255) / 256, 256, 0, stream>>>(dst, deg, E, Ws[0], Ws[1], Ws[2], Ws[3],
                                                      Wt[0], Wt[1], Wt[2], Wt[3]);
    }
    scan1<<<nb, 256, 0, stream>>>(deg, off, partial, dinv, N);
    scan2<<<1, 256, 0, stream>>>(partial, nb);
    scan3<<<(N + 256) / 256, 256, 0, stream>>>(off, partial, cursor, N, E);
    {
        int tot = E + N * 128 + HID;
        fill_cvt<<<(tot + 255) / 256, 256, 0, stream>>>(src, dst, cursor, srcs, E,
                                                        x, dinv, xb, N * 128, gsum);
    }

    for (int l = 0; l < 4; l++) {
        const int K = (l == 0) ? 128 : HID;
        const ushort_t* xin = (l == 0) ? xb : ho;
        dim3 ga((N * 64 + 255) / 256, K / 128);   // y = column tile (slow axis)
        if (l == 0)
            csr_agg<64><<<ga, 256, 0, stream>>>((const uint_t*)xin, off, srcs, dinv,
                                                (uint_t*)axb, N);
        else
            csr_agg<256><<<ga, 256, 0, stream>>>((const uint_t*)xin, off, srcs, dinv,
                                                 (uint_t*)axb, N);
        dim3 gg(HID / 128, (N + 127) / 128);
        gemm_mfma<<<gg, 256, 0, stream>>>(axb, Wt[l], bs[l], hb, N, K);
        if (l < 3)
            ln_relu_bf16<true><<<(N * 64 + 255) / 256, 256, 0, stream>>>(hb, gamma, beta,
                                                                         dinv, ho, N);
        else
            ln_relu_bf16<false><<<(N * 64 + 255) / 256, 256, 0, stream>>>(hb, gamma, beta,
                                                                          dinv, ho, N);
    }
    colsum<<<512, 256, 0, stream>>>(ho, gsum, N);
    out_kernel<<<1, 256, 0, stream>>>(gsum, Wout, bout, out, N);
}

// Round 7
// 412.425 us; speedup vs baseline: 1.1635x; 1.1635x over previous
//
#include <hip/hip_runtime.h>

#define HID 512
#define OUTD 7
#define EPSV 1e-5f

typedef __attribute__((ext_vector_type(8))) short bf16x8;
typedef __attribute__((ext_vector_type(4))) float f32x4;
typedef __attribute__((ext_vector_type(2))) float f32x2;
typedef unsigned short ushort_t;
typedef unsigned int uint_t;
typedef unsigned char uchar_t;

// ---------------- bf16 helpers ----------------
__device__ __forceinline__ ushort_t f2bf(float f) {
    uint_t u = __float_as_uint(f);
    u = (u + 0x7fffu + ((u >> 16) & 1u)) >> 16;    // RNE
    return (ushort_t)u;
}
__device__ __forceinline__ float bflo(uint_t u) { return __uint_as_float(u << 16); }
__device__ __forceinline__ float bfhi(uint_t u) { return __uint_as_float(u & 0xffff0000u); }

// ---------------- fp8 e4m3 (OCP) helpers — HW cvt ----------------
// decode 4 fp8 (one dword) -> 4 floats
__device__ __forceinline__ void dec4(uint_t v, float* f) {
    f32x2 p0 = __builtin_amdgcn_cvt_pk_f32_fp8(v, false);   // bytes 0,1
    f32x2 p1 = __builtin_amdgcn_cvt_pk_f32_fp8(v, true);    // bytes 2,3
    f[0] = p0.x; f[1] = p0.y; f[2] = p1.x; f[3] = p1.y;
}
// encode 4 floats -> one dword of fp8
__device__ __forceinline__ uint_t enc4(float a, float b, float c, float d) {
    uint_t r = __builtin_amdgcn_cvt_pk_fp8_f32(a, b, 0, false);
    r = __builtin_amdgcn_cvt_pk_fp8_f32(c, d, r, true);
    return r;
}

// async global->LDS, 16B per lane; LDS dest is wave-uniform base + lane*16
__device__ __forceinline__ void gload_lds16(const ushort_t* g, ushort_t* l) {
    __builtin_amdgcn_global_load_lds(
        (const __attribute__((address_space(1))) uint_t*)g,
        (__attribute__((address_space(3))) uint_t*)l, 16, 0, 0);
}

// ---------------- setup ----------------

__global__ void zero_deg(int* __restrict__ deg, int N) {
    int i = blockIdx.x * blockDim.x + threadIdx.x;
    if (i < N) deg[i] = 0;
}

// degree count + all weight transposes (independent work, grid-partitioned)
__global__ void setup2(const int* __restrict__ dst, int* __restrict__ deg, int E,
                       const float* __restrict__ W0, const float* __restrict__ W1,
                       const float* __restrict__ W2, const float* __restrict__ W3,
                       ushort_t* __restrict__ T0, ushort_t* __restrict__ T1,
                       ushort_t* __restrict__ T2, ushort_t* __restrict__ T3) {
    int i = blockIdx.x * blockDim.x + threadIdx.x;
    if (i < E) { atomicAdd(&deg[dst[i]], 1); return; }
    i -= E;
    const int S0 = 128 * HID, S1 = HID * HID;
    if (i < S0) { int k = i / HID, n = i % HID; T0[(size_t)n * 128 + k] = f2bf(W0[i]); return; }
    i -= S0;
    if (i < S1) { int k = i / HID, n = i % HID; T1[(size_t)n * HID + k] = f2bf(W1[i]); return; }
    i -= S1;
    if (i < S1) { int k = i / HID, n = i % HID; T2[(size_t)n * HID + k] = f2bf(W2[i]); return; }
    i -= S1;
    if (i < S1) { int k = i / HID, n = i % HID; T3[(size_t)n * HID + k] = f2bf(W3[i]); }
}

// ---------------- hierarchical scan (3 phases) ----------------

__global__ void scan1(const int* __restrict__ deg, int* __restrict__ off,
                      int* __restrict__ partial, float* __restrict__ dinv, int N) {
    __shared__ int s[256];
    const int t = threadIdx.x;
    const int i = blockIdx.x * 256 + t;
    int d = (i < N) ? deg[i] : 0;
    if (i < N) dinv[i] = rsqrtf((float)(d + 1));   // +1 self loop
    s[t] = d;
    __syncthreads();
#pragma unroll
    for (int ofs = 1; ofs < 256; ofs <<= 1) {
        int v = (t >= ofs) ? s[t - ofs] : 0;
        __syncthreads();
        s[t] += v;
        __syncthreads();
    }
    if (i < N) off[i] = s[t] - d;
    if (t == 255) partial[blockIdx.x] = s[255];
}

__global__ void scan2(int* __restrict__ partial, int nb) {
    __shared__ int s[256];
    const int t = threadIdx.x;
    int d = (t < nb) ? partial[t] : 0;
    s[t] = d;
    __syncthreads();
#pragma unroll
    for (int ofs = 1; ofs < 256; ofs <<= 1) {
        int v = (t >= ofs) ? s[t - ofs] : 0;
        __syncthreads();
        s[t] += v;
        __syncthreads();
    }
    if (t < nb) partial[t] = s[t] - d;
}

__global__ void scan3(int* __restrict__ off, const int* __restrict__ partial,
                      int* __restrict__ cursor, int N, int E) {
    int i = blockIdx.x * blockDim.x + threadIdx.x;
    if (i < N) {
        int v = off[i] + partial[i >> 8];
        off[i] = v;
        cursor[i] = v;
    } else if (i == N) {
        off[N] = E;
    }
}

// ---------------- fused: CSR fill + x -> fp8*dinv + gsum zero ----------------
// x pairs: thread i handles elements 2i,2i+1 (same row; K=128 even)

__global__ void fill_cvt(const int* __restrict__ src, const int* __restrict__ dst,
                         int* __restrict__ cursor, int* __restrict__ srcs, int E,
                         const float* __restrict__ x, const float* __restrict__ dinv,
                         ushort_t* __restrict__ xb, int pairs, float* __restrict__ gsum) {
    int i = blockIdx.x * blockDim.x + threadIdx.x;
    if (i < E) { int p = atomicAdd(&cursor[dst[i]], 1); srcs[p] = src[i]; return; }
    i -= E;
    if (i < pairs) {
        float dr = dinv[i >> 6];                      // row = 2i/128
        float a = x[2 * i] * dr, b = x[2 * i + 1] * dr;
        uint_t d = __builtin_amdgcn_cvt_pk_fp8_f32(a, b, 0, false);
        xb[i] = (ushort_t)(d & 0xffffu);
        return;
    }
    i -= pairs;
    if (i < HID) gsum[i] = 0.0f;
}

// ---------------- aggregation: full-row fp8 gather, one wave per row ----------------
// Input xs is fp8, PRE-SCALED by dinv. ax[r] = bf16( dinv[r] * (xs[r] + sum xs[nbr]) ).
// K=512: 8 B/lane (uint2) => 8 cache lines/edge (vs 16 for bf16 — the point).

__global__ __launch_bounds__(256) void csr_agg_512(
        const uchar_t* __restrict__ xs, const int* __restrict__ off,
        const int* __restrict__ srcs, const float* __restrict__ dinv,
        ushort_t* __restrict__ ax, int N) {
    int gtid = blockIdx.x * 256 + threadIdx.x;
    int r = gtid >> 6, lane = gtid & 63;
    if (r >= N) return;
    const uint2* xb = (const uint2*)xs;    // row stride = 64 uint2
    float a[8];
    {
        uint2 v = xb[(size_t)r * 64 + lane];
        dec4(v.x, a); dec4(v.y, a + 4);
    }
    int e = off[r];
    const int e1 = off[r + 1];
    for (; e + 8 <= e1; e += 8) {
        int si[8]; uint2 vi[8];
#pragma unroll
        for (int j = 0; j < 8; j++) si[j] = srcs[e + j];
#pragma unroll
        for (int j = 0; j < 8; j++) vi[j] = xb[(size_t)si[j] * 64 + lane];
#pragma unroll
        for (int j = 0; j < 8; j++) {
            float f[8]; dec4(vi[j].x, f); dec4(vi[j].y, f + 4);
#pragma unroll
            for (int q = 0; q < 8; q++) a[q] += f[q];
        }
    }
    for (; e < e1; e++) {
        uint2 v = xb[(size_t)srcs[e] * 64 + lane];
        float f[8]; dec4(v.x, f); dec4(v.y, f + 4);
#pragma unroll
        for (int q = 0; q < 8; q++) a[q] += f[q];
    }
    float dr = dinv[r];
    uint4 o;
    o.x = (uint_t)f2bf(a[0] * dr) | ((uint_t)f2bf(a[1] * dr) << 16);
    o.y = (uint_t)f2bf(a[2] * dr) | ((uint_t)f2bf(a[3] * dr) << 16);
    o.z = (uint_t)f2bf(a[4] * dr) | ((uint_t)f2bf(a[5] * dr) << 16);
    o.w = (uint_t)f2bf(a[6] * dr) | ((uint_t)f2bf(a[7] * dr) << 16);
    ((uint4*)ax)[(size_t)r * 64 + lane] = o;   // cols [8*lane, 8*lane+8)
}

// K=128: 2 B/lane (ushort) => 2 lines/edge
__global__ __launch_bounds__(256) void csr_agg_128(
        const uchar_t* __restrict__ xs, const int* __restrict__ off,
        const int* __restrict__ srcs, const float* __restrict__ dinv,
        ushort_t* __restrict__ ax, int N) {
    int gtid = blockIdx.x * 256 + threadIdx.x;
    int r = gtid >> 6, lane = gtid & 63;
    if (r >= N) return;
    const ushort_t* xb = (const ushort_t*)xs;   // row stride = 64 ushort
    float a0, a1;
    {
        uint_t v = xb[(size_t)r * 64 + lane];
        f32x2 p = __builtin_amdgcn_cvt_pk_f32_fp8(v, false);
        a0 = p.x; a1 = p.y;
    }
    int e = off[r];
    const int e1 = off[r + 1];
    for (; e + 8 <= e1; e += 8) {
        int si[8]; uint_t vi[8];
#pragma unroll
        for (int j = 0; j < 8; j++) si[j] = srcs[e + j];
#pragma unroll
        for (int j = 0; j < 8; j++) vi[j] = xb[(size_t)si[j] * 64 + lane];
#pragma unroll
        for (int j = 0; j < 8; j++) {
            f32x2 p = __builtin_amdgcn_cvt_pk_f32_fp8(vi[j], false);
            a0 += p.x; a1 += p.y;
        }
    }
    for (; e < e1; e++) {
        uint_t v = xb[(size_t)srcs[e] * 64 + lane];
        f32x2 p = __builtin_amdgcn_cvt_pk_f32_fp8(v, false);
        a0 += p.x; a1 += p.y;
    }
    float dr = dinv[r];
    ((uint_t*)ax)[(size_t)r * 64 + lane] =
        (uint_t)f2bf(a0 * dr) | ((uint_t)f2bf(a1 * dr) << 16);   // cols 2*lane, 2*lane+1
}

// ---------------- MFMA GEMM: C[M x 512] = A[M x K](bf16) @ Wt[512 x K]^T + bias, bf16 out ----
// 128x128 tile, BK=32, 4 waves (64x64 each, 4x4 frags of 16x16x32).
// LDS chunk-major [chunk 0..3][row 0..127][8 bf16] — global_load_lds-compatible,
// conflict-free ds_read_b128 (lane stride 16B).

__global__ __launch_bounds__(256) void gemm_mfma(
        const ushort_t* __restrict__ A, const ushort_t* __restrict__ Wt,
        const float* __restrict__ bias, ushort_t* __restrict__ C, int M, int K) {
    __shared__ __align__(16) ushort_t As[4 * 128 * 8];   // 8 KB
    __shared__ __align__(16) ushort_t Bs[4 * 128 * 8];   // 8 KB
    const int t = threadIdx.x;
    const int wave = t >> 6, lane = t & 63;
    const int m0 = blockIdx.y * 128, n0 = blockIdx.x * 128;
    const int wm = (wave & 1) * 64, wn = (wave >> 1) * 64;
    const int quad = lane >> 4, l16 = lane & 15;

    f32x4 acc[4][4];
#pragma unroll
    for (int i = 0; i < 4; i++)
#pragma unroll
        for (int j = 0; j < 4; j++) acc[i][j] = (f32x4){0.f, 0.f, 0.f, 0.f};

    for (int k0 = 0; k0 < K; k0 += 32) {
        const int c = wave;   // wave stages its own k-chunk
#pragma unroll
        for (int h = 0; h < 2; h++) {
            int gm = m0 + 64 * h + lane;
            if (gm >= M) gm = M - 1;
            gload_lds16(A + (size_t)gm * K + k0 + c * 8, &As[(c * 128 + 64 * h) * 8]);
            gload_lds16(Wt + (size_t)(n0 + 64 * h + lane) * K + k0 + c * 8,
                        &Bs[(c * 128 + 64 * h) * 8]);
        }
        __syncthreads();
        bf16x8 af[4], bfr[4];
#pragma unroll
        for (int i = 0; i < 4; i++) {
            af[i]  = *(const bf16x8*)&As[(quad * 128 + wm + i * 16 + l16) * 8];
            bfr[i] = *(const bf16x8*)&Bs[(quad * 128 + wn + i * 16 + l16) * 8];
        }
#pragma unroll
        for (int i = 0; i < 4; i++)
#pragma unroll
            for (int jn = 0; jn < 4; jn++)
                acc[i][jn] = __builtin_amdgcn_mfma_f32_16x16x32_bf16(
                                 af[i], bfr[jn], acc[i][jn], 0, 0, 0);
        __syncthreads();
    }
    // epilogue: + bias, pack bf16. D: col = lane&15, row = quad*4 + reg
#pragma unroll
    for (int i = 0; i < 4; i++) {
#pragma unroll
        for (int jn = 0; jn < 4; jn++) {
            int gn = n0 + wn + jn * 16 + l16;
            float bv = bias[gn];
#pragma unroll
            for (int rg = 0; rg < 4; rg++) {
                int gm = m0 + wm + i * 16 + quad * 4 + rg;
                if (gm < M) C[(size_t)gm * HID + gn] = f2bf(acc[i][jn][rg] + bv);
            }
        }
    }
}

// ---------------- LayerNorm + ReLU ----------------
// MODE 0: bf16 out (last layer, feeds pool). MODE 1: fp8 out, pre-scaled by dinv (feeds agg).

template<int MODE>
__global__ void ln_relu(const ushort_t* __restrict__ h, const float* __restrict__ gamma,
                        const float* __restrict__ beta, const float* __restrict__ dinv,
                        void* __restrict__ optr, int N) {
    int gtid = blockIdx.x * blockDim.x + threadIdx.x;
    int r = gtid >> 6, lane = gtid & 63;
    if (r >= N) return;
    uint4 v = ((const uint4*)(h + (size_t)r * HID))[lane];
    float f[8] = {bflo(v.x), bfhi(v.x), bflo(v.y), bfhi(v.y),
                  bflo(v.z), bfhi(v.z), bflo(v.w), bfhi(v.w)};
    float s = 0.f, q = 0.f;
#pragma unroll
    for (int j = 0; j < 8; j++) { s += f[j]; q += f[j] * f[j]; }
#pragma unroll
    for (int ofs = 32; ofs > 0; ofs >>= 1) {
        s += __shfl_xor(s, ofs);
        q += __shfl_xor(q, ofs);
    }
    float mu  = s * (1.0f / HID);
    float var = q * (1.0f / HID) - mu * mu;
    float rs  = rsqrtf(var + EPSV);
    float dr  = (MODE == 1) ? dinv[r] : 1.0f;
    const float4* gp = (const float4*)gamma;
    const float4* bp = (const float4*)beta;
    float4 g0 = gp[2 * lane], g1 = gp[2 * lane + 1];
    float4 b0 = bp[2 * lane], b1 = bp[2 * lane + 1];
    float gg[8] = {g0.x, g0.y, g0.z, g0.w, g1.x, g1.y, g1.z, g1.w};
    float bb[8] = {b0.x, b0.y, b0.z, b0.w, b1.x, b1.y, b1.z, b1.w};
    float o[8];
#pragma unroll
    for (int j = 0; j < 8; j++)
        o[j] = fmaxf((f[j] - mu) * rs * gg[j] + bb[j], 0.f) * dr;
    if (MODE == 0) {
        uint4 ov;
        ov.x = (uint_t)f2bf(o[0]) | ((uint_t)f2bf(o[1]) << 16);
        ov.y = (uint_t)f2bf(o[2]) | ((uint_t)f2bf(o[3]) << 16);
        ov.z = (uint_t)f2bf(o[4]) | ((uint_t)f2bf(o[5]) << 16);
        ov.w = (uint_t)f2bf(o[6]) | ((uint_t)f2bf(o[7]) << 16);
        ((uint4*)optr)[(size_t)r * 64 + lane] = ov;
    } else {
        uint2 ov;
        ov.x = enc4(o[0], o[1], o[2], o[3]);
        ov.y = enc4(o[4], o[5], o[6], o[7]);
        ((uint2*)optr)[(size_t)r * 64 + lane] = ov;   // fp8 row: 8 B/lane
    }
}

// ---------------- mean pool + output head ----------------

__global__ void colsum(const ushort_t* __restrict__ h, float* __restrict__ gsum, int N) {
    int t = threadIdx.x;   // 256 -> 2 cols each
    float a0 = 0.f, a1 = 0.f;
    for (int r = blockIdx.x; r < N; r += gridDim.x) {
        uint_t u = ((const uint_t*)(h + (size_t)r * HID))[t];
        a0 += bflo(u);
        a1 += bfhi(u);
    }
    atomicAdd(&gsum[2 * t], a0);
    atomicAdd(&gsum[2 * t + 1], a1);
}

__global__ void out_kernel(const float* __restrict__ gsum, const float* __restrict__ Wout,
                           const float* __restrict__ bout, float* __restrict__ out, int N) {
    __shared__ float red[256];
    int t = threadIdx.x;
    float g0 = gsum[2 * t], g1 = gsum[2 * t + 1];
    float invn = 1.0f / (float)N;
    for (int o = 0; o < OUTD; o++) {
        float p = g0 * Wout[(2 * t) * OUTD + o] + g1 * Wout[(2 * t + 1) * OUTD + o];
        red[t] = p;
        __syncthreads();
        for (int sft = 128; sft > 0; sft >>= 1) {
            if (t < sft) red[t] += red[t + sft];
            __syncthreads();
        }
        if (t == 0) out[o] = red[0] * invn + bout[o];
        __syncthreads();
    }
}

// ---------------- launch ----------------

extern "C" void kernel_launch(void* const* d_in, const int* in_sizes, int n_in,
                              void* d_out, int out_size, void* d_ws, size_t ws_size,
                              hipStream_t stream) {
    const float* x  = (const float*)d_in[0];
    const int*   ei = (const int*)d_in[1];
    const int N = in_sizes[0] / 128;
    const int E = in_sizes[1] / 2;
    const int* src = ei;
    const int* dst = ei + E;
    const float* Ws[4] = {(const float*)d_in[2], (const float*)d_in[4],
                          (const float*)d_in[6], (const float*)d_in[8]};
    const float* bs[4] = {(const float*)d_in[3], (const float*)d_in[5],
                          (const float*)d_in[7], (const float*)d_in[9]};
    const float* gamma = (const float*)d_in[10];
    const float* beta  = (const float*)d_in[11];
    const float* Wout  = (const float*)d_in[12];
    const float* bout  = (const float*)d_in[13];
    float* out = (float*)d_out;

    // workspace layout (16B-aligned chunks first)
    char* p = (char*)d_ws;
    ushort_t* axb = (ushort_t*)p;  p += sizeof(ushort_t) * (size_t)N * HID;   // agg out / gemm A / l3-ln out
    ushort_t* hb  = (ushort_t*)p;  p += sizeof(ushort_t) * (size_t)N * HID;   // gemm out (pre-LN)
    uchar_t*  ho8 = (uchar_t*)p;   p += (size_t)N * HID;                      // fp8 LN out (agg input)
    uchar_t*  xb8 = ho8;           // alias: fp8 x (N*128B, pre-scaled) until ln(l0) overwrites
    ushort_t* Wt[4];
    Wt[0] = (ushort_t*)p;          p += sizeof(ushort_t) * 128 * HID;
    Wt[1] = (ushort_t*)p;          p += sizeof(ushort_t) * HID * HID;
    Wt[2] = (ushort_t*)p;          p += sizeof(ushort_t) * HID * HID;
    Wt[3] = (ushort_t*)p;          p += sizeof(ushort_t) * HID * HID;
    float* dinv = (float*)p;       p += sizeof(float) * N;
    float* gsum = (float*)p;       p += sizeof(float) * HID;
    int* deg    = (int*)p;         p += sizeof(int) * N;
    int* off    = (int*)p;         p += sizeof(int) * (N + 4);
    int* cursor = (int*)p;         p += sizeof(int) * N;
    int* partial= (int*)p;         p += sizeof(int) * 256;
    int* srcs   = (int*)p;         // E ints

    const int nb = (N + 255) / 256;

    // ---- setup: CSR build + conversions (once) ----
    zero_deg<<<(N + 255) / 256, 256, 0, stream>>>(deg, N);
    {
        int tot = E + 128 * HID + 3 * HID * HID;
        setup2<<<(tot + 255) / 256, 256, 0, stream>>>(dst, deg, E, Ws[0], Ws[1], Ws[2], Ws[3],
                                                      Wt[0], Wt[1], Wt[2], Wt[3]);
    }
    scan1<<<nb, 256, 0, stream>>>(deg, off, partial, dinv, N);
    scan2<<<1, 256, 0, stream>>>(partial, nb);
    scan3<<<(N + 256) / 256, 256, 0, stream>>>(off, partial, cursor, N, E);
    {
        int pairs = N * 64;   // N*128/2
        int tot = E + pairs + HID;
        fill_cvt<<<(tot + 255) / 256, 256, 0, stream>>>(src, dst, cursor, srcs, E,
                                                        x, dinv, (ushort_t*)xb8, pairs, gsum);
    }

    for (int l = 0; l < 4; l++) {
        const int K = (l == 0) ? 128 : HID;
        // agg: fp8 gather -> bf16 axb
        if (l == 0)
            csr_agg_128<<<(N * 64 + 255) / 256, 256, 0, stream>>>(xb8, off, srcs, dinv, axb, N);
        else
            csr_agg_512<<<(N * 64 + 255) / 256, 256, 0, stream>>>(ho8, off, srcs, dinv, axb, N);
        // gemm: bf16 MFMA
        dim3 gg(HID / 128, (N + 127) / 128);
        gemm_mfma<<<gg, 256, 0, stream>>>(axb, Wt[l], bs[l], hb, N, K);
        // ln+relu
        if (l < 3)
            ln_relu<1><<<(N * 64 + 255) / 256, 256, 0, stream>>>(hb, gamma, beta, dinv, ho8, N);
        else
            ln_relu<0><<<(N * 64 + 255) / 256, 256, 0, stream>>>(hb, gamma, beta, dinv, axb, N);
    }
    colsum<<<512, 256, 0, stream>>>(axb, gsum, N);
    out_kernel<<<1, 256, 0, stream>>>(gsum, Wout, bout, out, N);
}

// Round 8
// 395.284 us; speedup vs baseline: 1.2140x; 1.0434x over previous
//
#include <hip/hip_runtime.h>

#define HID 512
#define OUTD 7
#define EPSV 1e-5f

typedef __attribute__((ext_vector_type(8))) short bf16x8;
typedef __attribute__((ext_vector_type(4))) float f32x4;
typedef __attribute__((ext_vector_type(2))) float f32x2;
typedef unsigned short ushort_t;
typedef unsigned int uint_t;
typedef unsigned char uchar_t;

// ---------------- bf16 helpers ----------------
__device__ __forceinline__ ushort_t f2bf(float f) {
    uint_t u = __float_as_uint(f);
    u = (u + 0x7fffu + ((u >> 16) & 1u)) >> 16;    // RNE
    return (ushort_t)u;
}
__device__ __forceinline__ float bflo(uint_t u) { return __uint_as_float(u << 16); }
__device__ __forceinline__ float bfhi(uint_t u) { return __uint_as_float(u & 0xffff0000u); }

// ---------------- fp8 e4m3 (OCP) helpers — HW cvt ----------------
__device__ __forceinline__ void dec4(uint_t v, float* f) {
    f32x2 p0 = __builtin_amdgcn_cvt_pk_f32_fp8(v, false);   // bytes 0,1
    f32x2 p1 = __builtin_amdgcn_cvt_pk_f32_fp8(v, true);    // bytes 2,3
    f[0] = p0.x; f[1] = p0.y; f[2] = p1.x; f[3] = p1.y;
}
__device__ __forceinline__ uint_t enc4(float a, float b, float c, float d) {
    uint_t r = __builtin_amdgcn_cvt_pk_fp8_f32(a, b, 0, false);
    r = __builtin_amdgcn_cvt_pk_fp8_f32(c, d, r, true);
    return r;
}

// async global->LDS, 16B per lane; LDS dest is wave-uniform base + lane*16
__device__ __forceinline__ void gload_lds16(const ushort_t* g, ushort_t* l) {
    __builtin_amdgcn_global_load_lds(
        (const __attribute__((address_space(1))) uint_t*)g,
        (__attribute__((address_space(3))) uint_t*)l, 16, 0, 0);
}
__device__ __forceinline__ void gload_lds16_u8(const uchar_t* g, uchar_t* l) {
    __builtin_amdgcn_global_load_lds(
        (const __attribute__((address_space(1))) uint_t*)g,
        (__attribute__((address_space(3))) uint_t*)l, 16, 0, 0);
}

// ---------------- setup ----------------

__global__ void zero_deg(int* __restrict__ deg, int N) {
    int i = blockIdx.x * blockDim.x + threadIdx.x;
    if (i < N) deg[i] = 0;
}

// degree count + all weight transposes (independent work, grid-partitioned)
__global__ void setup2(const int* __restrict__ dst, int* __restrict__ deg, int E,
                       const float* __restrict__ W0, const float* __restrict__ W1,
                       const float* __restrict__ W2, const float* __restrict__ W3,
                       ushort_t* __restrict__ T0, ushort_t* __restrict__ T1,
                       ushort_t* __restrict__ T2, ushort_t* __restrict__ T3) {
    int i = blockIdx.x * blockDim.x + threadIdx.x;
    if (i < E) { atomicAdd(&deg[dst[i]], 1); return; }
    i -= E;
    const int S0 = 128 * HID, S1 = HID * HID;
    if (i < S0) { int k = i / HID, n = i % HID; T0[(size_t)n * 128 + k] = f2bf(W0[i]); return; }
    i -= S0;
    if (i < S1) { int k = i / HID, n = i % HID; T1[(size_t)n * HID + k] = f2bf(W1[i]); return; }
    i -= S1;
    if (i < S1) { int k = i / HID, n = i % HID; T2[(size_t)n * HID + k] = f2bf(W2[i]); return; }
    i -= S1;
    if (i < S1) { int k = i / HID, n = i % HID; T3[(size_t)n * HID + k] = f2bf(W3[i]); }
}

// ---------------- hierarchical scan (2 phases) ----------------

__global__ void scan1(const int* __restrict__ deg, int* __restrict__ off,
                      int* __restrict__ partial, float* __restrict__ dinv, int N) {
    __shared__ int s[256];
    const int t = threadIdx.x;
    const int i = blockIdx.x * 256 + t;
    int d = (i < N) ? deg[i] : 0;
    if (i < N) dinv[i] = rsqrtf((float)(d + 1));   // +1 self loop
    s[t] = d;
    __syncthreads();
#pragma unroll
    for (int ofs = 1; ofs < 256; ofs <<= 1) {
        int v = (t >= ofs) ? s[t - ofs] : 0;
        __syncthreads();
        s[t] += v;
        __syncthreads();
    }
    if (i < N) off[i] = s[t] - d;
    if (t == 255) partial[blockIdx.x] = s[255];
}

// fused scan2+scan3: every block redundantly scans the <=256 partials, then adds
__global__ void scan23(int* __restrict__ off, const int* __restrict__ partial,
                       int* __restrict__ cursor, int N, int E, int nb) {
    __shared__ int s[256];
    __shared__ int ex[256];
    const int t = threadIdx.x;
    int d = (t < nb) ? partial[t] : 0;
    s[t] = d;
    __syncthreads();
#pragma unroll
    for (int ofs = 1; ofs < 256; ofs <<= 1) {
        int v = (t >= ofs) ? s[t - ofs] : 0;
        __syncthreads();
        s[t] += v;
        __syncthreads();
    }
    ex[t] = s[t] - d;
    __syncthreads();
    int i = blockIdx.x * 256 + t;
    if (i < N) {
        int v = off[i] + ex[i >> 8];
        off[i] = v;
        cursor[i] = v;
    } else if (i == N) {
        off[N] = E;
    }
}

// ---------------- fused: CSR fill + x -> fp8*dinv + gsum zero ----------------

__global__ void fill_cvt(const int* __restrict__ src, const int* __restrict__ dst,
                         int* __restrict__ cursor, int* __restrict__ srcs, int E,
                         const float* __restrict__ x, const float* __restrict__ dinv,
                         ushort_t* __restrict__ xb, int pairs, float* __restrict__ gsum) {
    int i = blockIdx.x * blockDim.x + threadIdx.x;
    if (i < E) { int p = atomicAdd(&cursor[dst[i]], 1); srcs[p] = src[i]; return; }
    i -= E;
    if (i < pairs) {
        float dr = dinv[i >> 6];                      // row = 2i/128
        float a = x[2 * i] * dr, b = x[2 * i + 1] * dr;
        uint_t d = __builtin_amdgcn_cvt_pk_fp8_f32(a, b, 0, false);
        xb[i] = (ushort_t)(d & 0xffffu);
        return;
    }
    i -= pairs;
    if (i < HID) gsum[i] = 0.0f;
}

// ---------------- aggregation: full-row fp8 gather -> fp8 out ----------------
// Input xs is fp8, PRE-SCALED by dinv. ax[r] = fp8( dinv[r] * (xs[r] + sum xs[nbr]) ).

__global__ __launch_bounds__(256) void csr_agg_512(
        const uchar_t* __restrict__ xs, const int* __restrict__ off,
        const int* __restrict__ srcs, const float* __restrict__ dinv,
        uchar_t* __restrict__ ax, int N) {
    int gtid = blockIdx.x * 256 + threadIdx.x;
    int r = gtid >> 6, lane = gtid & 63;
    if (r >= N) return;
    const uint2* xb = (const uint2*)xs;    // row stride = 64 uint2
    float a[8];
    {
        uint2 v = xb[(size_t)r * 64 + lane];
        dec4(v.x, a); dec4(v.y, a + 4);
    }
    int e = off[r];
    const int e1 = off[r + 1];
    for (; e + 8 <= e1; e += 8) {
        int si[8]; uint2 vi[8];
#pragma unroll
        for (int j = 0; j < 8; j++) si[j] = srcs[e + j];
#pragma unroll
        for (int j = 0; j < 8; j++) vi[j] = xb[(size_t)si[j] * 64 + lane];
#pragma unroll
        for (int j = 0; j < 8; j++) {
            float f[8]; dec4(vi[j].x, f); dec4(vi[j].y, f + 4);
#pragma unroll
            for (int q = 0; q < 8; q++) a[q] += f[q];
        }
    }
    for (; e < e1; e++) {
        uint2 v = xb[(size_t)srcs[e] * 64 + lane];
        float f[8]; dec4(v.x, f); dec4(v.y, f + 4);
#pragma unroll
        for (int q = 0; q < 8; q++) a[q] += f[q];
    }
    float dr = dinv[r];
    uint2 o;
    o.x = enc4(a[0] * dr, a[1] * dr, a[2] * dr, a[3] * dr);
    o.y = enc4(a[4] * dr, a[5] * dr, a[6] * dr, a[7] * dr);
    ((uint2*)ax)[(size_t)r * 64 + lane] = o;
}

__global__ __launch_bounds__(256) void csr_agg_128(
        const uchar_t* __restrict__ xs, const int* __restrict__ off,
        const int* __restrict__ srcs, const float* __restrict__ dinv,
        uchar_t* __restrict__ ax, int N) {
    int gtid = blockIdx.x * 256 + threadIdx.x;
    int r = gtid >> 6, lane = gtid & 63;
    if (r >= N) return;
    const ushort_t* xb = (const ushort_t*)xs;   // row stride = 64 ushort
    float a0, a1;
    {
        uint_t v = xb[(size_t)r * 64 + lane];
        f32x2 p = __builtin_amdgcn_cvt_pk_f32_fp8(v, false);
        a0 = p.x; a1 = p.y;
    }
    int e = off[r];
    const int e1 = off[r + 1];
    for (; e + 8 <= e1; e += 8) {
        int si[8]; uint_t vi[8];
#pragma unroll
        for (int j = 0; j < 8; j++) si[j] = srcs[e + j];
#pragma unroll
        for (int j = 0; j < 8; j++) vi[j] = xb[(size_t)si[j] * 64 + lane];
#pragma unroll
        for (int j = 0; j < 8; j++) {
            f32x2 p = __builtin_amdgcn_cvt_pk_f32_fp8(vi[j], false);
            a0 += p.x; a1 += p.y;
        }
    }
    for (; e < e1; e++) {
        uint_t v = xb[(size_t)srcs[e] * 64 + lane];
        f32x2 p = __builtin_amdgcn_cvt_pk_f32_fp8(v, false);
        a0 += p.x; a1 += p.y;
    }
    float dr = dinv[r];
    uint_t d = __builtin_amdgcn_cvt_pk_fp8_f32(a0 * dr, a1 * dr, 0, false);
    ((ushort_t*)ax)[(size_t)r * 64 + lane] = (ushort_t)(d & 0xffffu);
}

// ---------------- MFMA GEMM: C = A(fp8)[M x K] @ Wt(bf16)[512 x K]^T + bias, bf16 out ----
// 128x128 tile, BK=64, 4 waves (64x64 each, 4x4 frags of 16x16x32).
// As: fp8 chunk-major [4][128 rows][16 B], Bs: bf16 [8][128 rows][8 elems].
// A frags cvt fp8->f32 (HW) -> bf16 (truncation pack) after ds_read_b64.

__global__ __launch_bounds__(256) void gemm_mfma(
        const uchar_t* __restrict__ A, const ushort_t* __restrict__ Wt,
        const float* __restrict__ bias, ushort_t* __restrict__ C, int M, int K) {
    __shared__ __align__(16) uchar_t  As[4 * 128 * 16];   // 8 KB
    __shared__ __align__(16) ushort_t Bs[8 * 128 * 8];    // 16 KB
    const int t = threadIdx.x;
    const int wave = t >> 6, lane = t & 63;
    const int m0 = blockIdx.y * 128, n0 = blockIdx.x * 128;
    const int wm = (wave & 1) * 64, wn = (wave >> 1) * 64;
    const int quad = lane >> 4, l16 = lane & 15;

    f32x4 acc[4][4];
#pragma unroll
    for (int i = 0; i < 4; i++)
#pragma unroll
        for (int j = 0; j < 4; j++) acc[i][j] = (f32x4){0.f, 0.f, 0.f, 0.f};

    for (int k0 = 0; k0 < K; k0 += 64) {
        // A: wave w stages fp8 chunk w (k-bytes k0+w*16..+16) for all 128 rows
#pragma unroll
        for (int h = 0; h < 2; h++) {
            int gm = m0 + 64 * h + lane;
            if (gm >= M) gm = M - 1;
            gload_lds16_u8(A + (size_t)gm * K + k0 + wave * 16,
                           &As[(wave * 128 + 64 * h) * 16]);
        }
        // B: wave w stages bf16 chunks 2w,2w+1 (k-elems cb*8..+8)
#pragma unroll
        for (int h = 0; h < 4; h++) {
            int cb = wave * 2 + (h >> 1);
            int row = (h & 1) * 64 + lane;
            gload_lds16(Wt + (size_t)(n0 + row) * K + k0 + cb * 8,
                        &Bs[(cb * 128 + (h & 1) * 64) * 8]);
        }
        __syncthreads();
#pragma unroll
        for (int kk = 0; kk < 2; kk++) {
            bf16x8 af[4], bfr[4];
#pragma unroll
            for (int jn = 0; jn < 4; jn++)
                bfr[jn] = *(const bf16x8*)&Bs[((kk * 4 + quad) * 128 + wn + jn * 16 + l16) * 8];
#pragma unroll
            for (int i = 0; i < 4; i++) {
                uint2 v8 = *(const uint2*)&As[((kk * 2 + (quad >> 1)) * 128 + wm + i * 16 + l16) * 16
                                              + (quad & 1) * 8];
                f32x2 p0 = __builtin_amdgcn_cvt_pk_f32_fp8(v8.x, false);
                f32x2 p1 = __builtin_amdgcn_cvt_pk_f32_fp8(v8.x, true);
                f32x2 p2 = __builtin_amdgcn_cvt_pk_f32_fp8(v8.y, false);
                f32x2 p3 = __builtin_amdgcn_cvt_pk_f32_fp8(v8.y, true);
                union { uint_t u[4]; bf16x8 v; } pk;
                pk.u[0] = (__float_as_uint(p0.y) & 0xffff0000u) | (__float_as_uint(p0.x) >> 16);
                pk.u[1] = (__float_as_uint(p1.y) & 0xffff0000u) | (__float_as_uint(p1.x) >> 16);
                pk.u[2] = (__float_as_uint(p2.y) & 0xffff0000u) | (__float_as_uint(p2.x) >> 16);
                pk.u[3] = (__float_as_uint(p3.y) & 0xffff0000u) | (__float_as_uint(p3.x) >> 16);
                af[i] = pk.v;
            }
#pragma unroll
            for (int i = 0; i < 4; i++)
#pragma unroll
                for (int jn = 0; jn < 4; jn++)
                    acc[i][jn] = __builtin_amdgcn_mfma_f32_16x16x32_bf16(
                                     af[i], bfr[jn], acc[i][jn], 0, 0, 0);
        }
        __syncthreads();
    }
    // epilogue: + bias, pack bf16. D: col = lane&15, row = quad*4 + reg
#pragma unroll
    for (int i = 0; i < 4; i++) {
#pragma unroll
        for (int jn = 0; jn < 4; jn++) {
            int gn = n0 + wn + jn * 16 + l16;
            float bv = bias[gn];
#pragma unroll
            for (int rg = 0; rg < 4; rg++) {
                int gm = m0 + wm + i * 16 + quad * 4 + rg;
                if (gm < M) C[(size_t)gm * HID + gn] = f2bf(acc[i][jn][rg] + bv);
            }
        }
    }
}

// ---------------- LayerNorm + ReLU ----------------
// MODE 0: bf16 out in-place (last layer, feeds pool). MODE 1: fp8 out, pre-scaled by dinv.

template<int MODE>
__global__ void ln_relu(const ushort_t* __restrict__ h, const float* __restrict__ gamma,
                        const float* __restrict__ beta, const float* __restrict__ dinv,
                        void* __restrict__ optr, int N) {
    int gtid = blockIdx.x * blockDim.x + threadIdx.x;
    int r = gtid >> 6, lane = gtid & 63;
    if (r >= N) return;
    uint4 v = ((const uint4*)(h + (size_t)r * HID))[lane];
    float f[8] = {bflo(v.x), bfhi(v.x), bflo(v.y), bfhi(v.y),
                  bflo(v.z), bfhi(v.z), bflo(v.w), bfhi(v.w)};
    float s = 0.f, q = 0.f;
#pragma unroll
    for (int j = 0; j < 8; j++) { s += f[j]; q += f[j] * f[j]; }
#pragma unroll
    for (int ofs = 32; ofs > 0; ofs >>= 1) {
        s += __shfl_xor(s, ofs);
        q += __shfl_xor(q, ofs);
    }
    float mu  = s * (1.0f / HID);
    float var = q * (1.0f / HID) - mu * mu;
    float rs  = rsqrtf(var + EPSV);
    float dr  = (MODE == 1) ? dinv[r] : 1.0f;
    const float4* gp = (const float4*)gamma;
    const float4* bp = (const float4*)beta;
    float4 g0 = gp[2 * lane], g1 = gp[2 * lane + 1];
    float4 b0 = bp[2 * lane], b1 = bp[2 * lane + 1];
    float gg[8] = {g0.x, g0.y, g0.z, g0.w, g1.x, g1.y, g1.z, g1.w};
    float bb[8] = {b0.x, b0.y, b0.z, b0.w, b1.x, b1.y, b1.z, b1.w};
    float o[8];
#pragma unroll
    for (int j = 0; j < 8; j++)
        o[j] = fmaxf((f[j] - mu) * rs * gg[j] + bb[j], 0.f) * dr;
    if (MODE == 0) {
        uint4 ov;
        ov.x = (uint_t)f2bf(o[0]) | ((uint_t)f2bf(o[1]) << 16);
        ov.y = (uint_t)f2bf(o[2]) | ((uint_t)f2bf(o[3]) << 16);
        ov.z = (uint_t)f2bf(o[4]) | ((uint_t)f2bf(o[5]) << 16);
        ov.w = (uint_t)f2bf(o[6]) | ((uint_t)f2bf(o[7]) << 16);
        ((uint4*)optr)[(size_t)r * 64 + lane] = ov;
    } else {
        uint2 ov;
        ov.x = enc4(o[0], o[1], o[2], o[3]);
        ov.y = enc4(o[4], o[5], o[6], o[7]);
        ((uint2*)optr)[(size_t)r * 64 + lane] = ov;   // fp8 row: 8 B/lane
    }
}

// ---------------- mean pool + output head ----------------

__global__ void colsum(const ushort_t* __restrict__ h, float* __restrict__ gsum, int N) {
    int t = threadIdx.x;   // 256 -> 2 cols each
    float a0 = 0.f, a1 = 0.f;
    for (int r = blockIdx.x; r < N; r += gridDim.x) {
        uint_t u = ((const uint_t*)(h + (size_t)r * HID))[t];
        a0 += bflo(u);
        a1 += bfhi(u);
    }
    atomicAdd(&gsum[2 * t], a0);
    atomicAdd(&gsum[2 * t + 1], a1);
}

__global__ void out_kernel(const float* __restrict__ gsum, const float* __restrict__ Wout,
                           const float* __restrict__ bout, float* __restrict__ out, int N) {
    __shared__ float red[256];
    int t = threadIdx.x;
    float g0 = gsum[2 * t], g1 = gsum[2 * t + 1];
    float invn = 1.0f / (float)N;
    for (int o = 0; o < OUTD; o++) {
        float p = g0 * Wout[(2 * t) * OUTD + o] + g1 * Wout[(2 * t + 1) * OUTD + o];
        red[t] = p;
        __syncthreads();
        for (int sft = 128; sft > 0; sft >>= 1) {
            if (t < sft) red[t] += red[t + sft];
            __syncthreads();
        }
        if (t == 0) out[o] = red[0] * invn + bout[o];
        __syncthreads();
    }
}

// ---------------- launch ----------------

extern "C" void kernel_launch(void* const* d_in, const int* in_sizes, int n_in,
                              void* d_out, int out_size, void* d_ws, size_t ws_size,
                              hipStream_t stream) {
    const float* x  = (const float*)d_in[0];
    const int*   ei = (const int*)d_in[1];
    const int N = in_sizes[0] / 128;
    const int E = in_sizes[1] / 2;
    const int* src = ei;
    const int* dst = ei + E;
    const float* Ws[4] = {(const float*)d_in[2], (const float*)d_in[4],
                          (const float*)d_in[6], (const float*)d_in[8]};
    const float* bs[4] = {(const float*)d_in[3], (const float*)d_in[5],
                          (const float*)d_in[7], (const float*)d_in[9]};
    const float* gamma = (const float*)d_in[10];
    const float* beta  = (const float*)d_in[11];
    const float* Wout  = (const float*)d_in[12];
    const float* bout  = (const float*)d_in[13];
    float* out = (float*)d_out;

    // workspace layout (16B-aligned chunks first)
    char* p = (char*)d_ws;
    uchar_t*  axb = (uchar_t*)p;   p += (size_t)N * HID;                      // agg out fp8 (gemm A)
    ushort_t* hb  = (ushort_t*)p;  p += sizeof(ushort_t) * (size_t)N * HID;   // gemm out bf16 (ln in-place)
    uchar_t*  ho8 = (uchar_t*)p;   p += (size_t)N * HID;                      // fp8 LN out (agg input)
    uchar_t*  xb8 = ho8;           // alias: fp8 x (N*128B, pre-scaled) until ln(l0) overwrites
    ushort_t* Wt[4];
    Wt[0] = (ushort_t*)p;          p += sizeof(ushort_t) * 128 * HID;
    Wt[1] = (ushort_t*)p;          p += sizeof(ushort_t) * HID * HID;
    Wt[2] = (ushort_t*)p;          p += sizeof(ushort_t) * HID * HID;
    Wt[3] = (ushort_t*)p;          p += sizeof(ushort_t) * HID * HID;
    float* dinv = (float*)p;       p += sizeof(float) * N;
    float* gsum = (float*)p;       p += sizeof(float) * HID;
    int* deg    = (int*)p;         p += sizeof(int) * N;
    int* off    = (int*)p;         p += sizeof(int) * (N + 4);
    int* cursor = (int*)p;         p += sizeof(int) * N;
    int* partial= (int*)p;         p += sizeof(int) * 256;
    int* srcs   = (int*)p;         // E ints

    const int nb = (N + 255) / 256;

    // ---- setup: CSR build + conversions (once) ----
    zero_deg<<<(N + 255) / 256, 256, 0, stream>>>(deg, N);
    {
        int tot = E + 128 * HID + 3 * HID * HID;
        setup2<<<(tot + 255) / 256, 256, 0, stream>>>(dst, deg, E, Ws[0], Ws[1], Ws[2], Ws[3],
                                                      Wt[0], Wt[1], Wt[2], Wt[3]);
    }
    scan1<<<nb, 256, 0, stream>>>(deg, off, partial, dinv, N);
    scan23<<<(N + 256) / 256, 256, 0, stream>>>(off, partial, cursor, N, E, nb);
    {
        int pairs = N * 64;   // N*128/2
        int tot = E + pairs + HID;
        fill_cvt<<<(tot + 255) / 256, 256, 0, stream>>>(src, dst, cursor, srcs, E,
                                                        x, dinv, (ushort_t*)xb8, pairs, gsum);
    }

    for (int l = 0; l < 4; l++) {
        const int K = (l == 0) ? 128 : HID;
        // agg: fp8 gather -> fp8 axb
        if (l == 0)
            csr_agg_128<<<(N * 64 + 255) / 256, 256, 0, stream>>>(xb8, off, srcs, dinv, axb, N);
        else
            csr_agg_512<<<(N * 64 + 255) / 256, 256, 0, stream>>>(ho8, off, srcs, dinv, axb, N);
        // gemm: fp8-A x bf16-W MFMA
        dim3 gg(HID / 128, (N + 127) / 128);
        gemm_mfma<<<gg, 256, 0, stream>>>(axb, Wt[l], bs[l], hb, N, K);
        // ln+relu
        if (l < 3)
            ln_relu<1><<<(N * 64 + 255) / 256, 256, 0, stream>>>(hb, gamma, beta, dinv, ho8, N);
        else
            ln_relu<0><<<(N * 64 + 255) / 256, 256, 0, stream>>>(hb, gamma, beta, dinv, hb, N);
    }
    colsum<<<512, 256, 0, stream>>>(hb, gsum, N);
    out_kernel<<<1, 256, 0, stream>>>(gsum, Wout, bout, out, N);
}